// Round 1
// baseline (338.219 us; speedup 1.0000x reference)
//
#include <hip/hip_runtime.h>

// FANeuron: per-(b,f) sequential recurrence over T steps.
// One thread per chain. Bit-exact f32 (no FMA contraction) to match numpy ref.

#define UNROLL 8

__global__ __launch_bounds__(64, 1)
void fa_neuron_kernel(const float* __restrict__ x,
                      const float* __restrict__ vb,
                      const float* __restrict__ A,
                      const float* __restrict__ th,
                      const float* __restrict__ gain,
                      const float* __restrict__ tref,
                      float* __restrict__ out,
                      int B, int T, int F) {
#pragma clang fp contract(off)
    int tid = blockIdx.x * blockDim.x + threadIdx.x;
    if (tid >= B * F) return;
    int f = tid & (F - 1);      // F = 512 (power of two)
    int b = tid / F;

    const float vbf = vb[f];
    const float Af  = A[f];
    const float thf = th[f];
    const float gf  = gain[f];
    const float alpha = 0.001f;                       // f32(0.05/50.0)
    int rs = (int)fmaxf(ceilf(tref[f] / 0.05f), 1.0f); // ceil(tref/dt), >=1

    const float* xp    = x + (size_t)b * T * F + f;
    float* va_out      = out + (size_t)b * (T + 1) * F + f;
    float* sp_out      = out + (size_t)B * (T + 1) * F + (size_t)b * (T + 1) * F + f;

    // va_trace[:,0,:] = vb
    va_out[0] = vbf;

    float ema = 0.0f;
    int refc = 0;

    float cur[UNROLL], nxt[UNROLL];
#pragma unroll
    for (int u = 0; u < UNROLL; ++u) cur[u] = xp[(size_t)u * F];

    for (int t0 = 0; t0 < T; t0 += UNROLL) {
        // prefetch next group of x (independent of recurrence state)
        if (t0 + UNROLL < T) {
#pragma unroll
            for (int u = 0; u < UNROLL; ++u)
                nxt[u] = xp[(size_t)(t0 + UNROLL + u) * F];
        }
#pragma unroll
        for (int u = 0; u < UNROLL; ++u) {
            int t = t0 + u;
            float xt = cur[u] * gf;                 // scaled input
            float d1 = xt - ema;
            float emaN = ema + alpha * d1;          // separately-rounded (no FMA)
            ema = (t == 0) ? xt : emaN;             // EMA init at t==0
            float d2 = xt - ema;                    // uses UPDATED ema
            float va_cand = vbf - Af * d2;
            bool in_ref = refc > 0;
            bool cross = fabsf(va_cand - vbf) >= thf;
            bool fired = (!in_ref) && cross;
            float va_next = (in_ref || fired) ? vbf : va_cand;
            refc = in_ref ? (refc - 1) : refc;
            refc = fired ? rs : refc;
            va_out[(size_t)(t + 1) * F] = va_next;
            float spv = fired ? 1.0f : 0.0f;
            sp_out[(size_t)t * F] = spv;
            if (t == T - 1) sp_out[(size_t)T * F] = spv;  // last row duplicated
        }
#pragma unroll
        for (int u = 0; u < UNROLL; ++u) cur[u] = nxt[u];
    }
}

extern "C" void kernel_launch(void* const* d_in, const int* in_sizes, int n_in,
                              void* d_out, int out_size, void* d_ws, size_t ws_size,
                              hipStream_t stream) {
    const float* x    = (const float*)d_in[0];
    const float* vb   = (const float*)d_in[1];
    const float* A    = (const float*)d_in[2];
    const float* th   = (const float*)d_in[3];
    const float* gain = (const float*)d_in[4];
    const float* tref = (const float*)d_in[5];
    float* out = (float*)d_out;

    int F = in_sizes[1];                                   // 512
    long long BF = (long long)out_size / 2 - in_sizes[0];  // B*F = 8192
    int B = (int)(BF / F);                                 // 16
    int T = (int)(in_sizes[0] / BF);                       // 4096

    int threads = B * F;
    int block = 64;
    int grid = (threads + block - 1) / block;
    fa_neuron_kernel<<<grid, block, 0, stream>>>(x, vb, A, th, gain, tref, out, B, T, F);
}

// Round 2
// 240.347 us; speedup vs baseline: 1.4072x; 1.4072x over previous
//
#include <hip/hip_runtime.h>

// FANeuron split into:
//  K1 (scan): sequential per-chain recurrence, compute-only, stores exact
//             (ema, refc) state entering every L_CHUNK-step chunk.
//  K2 (emit): one thread per (chain, chunk) replays its chunk bit-exactly
//             from the seeded state and writes va_trace + spikes.
// Both use identical, separately-rounded f32 ops (contract off) so firing
// decisions match the monolithic version exactly.

#define L_CHUNK 256
#define K1_UNROLL 32
#define K2_UNROLL 8

__global__ __launch_bounds__(64, 1)
void fa_scan_kernel(const float* __restrict__ x,
                    const float* __restrict__ vb,
                    const float* __restrict__ A,
                    const float* __restrict__ th,
                    const float* __restrict__ gain,
                    const float* __restrict__ tref,
                    float* __restrict__ emas,   // [nchunks][N]
                    int*   __restrict__ rins,   // [nchunks][N]
                    int B, int T, int F) {
#pragma clang fp contract(off)
    int N = B * F;
    int i = blockIdx.x * blockDim.x + threadIdx.x;
    if (i >= N) return;
    int f = i % F;
    int b = i / F;
    const float vbf = vb[f], Af = A[f], thf = th[f], gf = gain[f];
    const float alpha = 0.001f;                        // f32(0.05/50)
    int rs = (int)fmaxf(ceilf(tref[f] / 0.05f), 1.0f);
    const float* xp = x + (size_t)b * T * F + f;

    float ema = 0.0f;
    int refc = 0;
    float cur[K1_UNROLL], nxt[K1_UNROLL];
#pragma unroll
    for (int u = 0; u < K1_UNROLL; ++u) cur[u] = xp[(size_t)u * F];

    for (int t0 = 0; t0 < T; t0 += K1_UNROLL) {
        if ((t0 % L_CHUNK) == 0) {
            int k = t0 / L_CHUNK;
            emas[(size_t)k * N + i] = ema;
            rins[(size_t)k * N + i] = refc;
        }
        if (t0 + K1_UNROLL < T) {
#pragma unroll
            for (int u = 0; u < K1_UNROLL; ++u)
                nxt[u] = xp[(size_t)(t0 + K1_UNROLL + u) * F];
        }
#pragma unroll
        for (int u = 0; u < K1_UNROLL; ++u) {
            int t = t0 + u;
            float xt = cur[u] * gf;
            float d1 = xt - ema;
            float emaN = ema + alpha * d1;
            ema = (t == 0) ? xt : emaN;
            float d2 = xt - ema;
            float va_cand = vbf - Af * d2;
            bool in_ref = refc > 0;
            bool cross = fabsf(va_cand - vbf) >= thf;
            bool fired = (!in_ref) && cross;
            refc = in_ref ? (refc - 1) : refc;
            refc = fired ? rs : refc;
        }
#pragma unroll
        for (int u = 0; u < K1_UNROLL; ++u) cur[u] = nxt[u];
    }
}

__global__ __launch_bounds__(256)
void fa_emit_kernel(const float* __restrict__ x,
                    const float* __restrict__ vb,
                    const float* __restrict__ A,
                    const float* __restrict__ th,
                    const float* __restrict__ gain,
                    const float* __restrict__ tref,
                    const float* __restrict__ emas,
                    const int*   __restrict__ rins,
                    float* __restrict__ out,
                    int B, int T, int F, int nchunks) {
#pragma clang fp contract(off)
    int N = B * F;
    int tid = blockIdx.x * blockDim.x + threadIdx.x;
    if (tid >= N * nchunks) return;
    int i = tid % N;
    int k = tid / N;
    int f = i % F;
    int b = i / F;
    const float vbf = vb[f], Af = A[f], thf = th[f], gf = gain[f];
    const float alpha = 0.001f;
    int rs = (int)fmaxf(ceilf(tref[f] / 0.05f), 1.0f);

    const float* xp = x + (size_t)b * T * F + f;
    float* va_out   = out + (size_t)b * (T + 1) * F + f;
    float* sp_out   = out + (size_t)B * (T + 1) * F + (size_t)b * (T + 1) * F + f;

    float ema = emas[tid];
    int refc  = rins[tid];
    if (k == 0) va_out[0] = vbf;   // va_trace[:,0,:] = vb

    int tbeg = k * L_CHUNK;
    int tend = tbeg + L_CHUNK;
    if (tend > T) tend = T;

    float cur[K2_UNROLL], nxt[K2_UNROLL];
#pragma unroll
    for (int u = 0; u < K2_UNROLL; ++u) cur[u] = xp[(size_t)(tbeg + u) * F];

    for (int t0 = tbeg; t0 < tend; t0 += K2_UNROLL) {
        if (t0 + K2_UNROLL < tend) {
#pragma unroll
            for (int u = 0; u < K2_UNROLL; ++u)
                nxt[u] = xp[(size_t)(t0 + K2_UNROLL + u) * F];
        }
#pragma unroll
        for (int u = 0; u < K2_UNROLL; ++u) {
            int t = t0 + u;
            float xt = cur[u] * gf;
            float d1 = xt - ema;
            float emaN = ema + alpha * d1;
            ema = (t == 0) ? xt : emaN;
            float d2 = xt - ema;
            float va_cand = vbf - Af * d2;
            bool in_ref = refc > 0;
            bool cross = fabsf(va_cand - vbf) >= thf;
            bool fired = (!in_ref) && cross;
            float va_next = (in_ref || fired) ? vbf : va_cand;
            refc = in_ref ? (refc - 1) : refc;
            refc = fired ? rs : refc;
            va_out[(size_t)(t + 1) * F] = va_next;
            float spv = fired ? 1.0f : 0.0f;
            sp_out[(size_t)t * F] = spv;
            if (t == T - 1) sp_out[(size_t)T * F] = spv;
        }
#pragma unroll
        for (int u = 0; u < K2_UNROLL; ++u) cur[u] = nxt[u];
    }
}

// Fallback: round-1 monolithic kernel (used only if ws is too small).
__global__ __launch_bounds__(64, 1)
void fa_neuron_mono(const float* __restrict__ x,
                    const float* __restrict__ vb,
                    const float* __restrict__ A,
                    const float* __restrict__ th,
                    const float* __restrict__ gain,
                    const float* __restrict__ tref,
                    float* __restrict__ out,
                    int B, int T, int F) {
#pragma clang fp contract(off)
    int tid = blockIdx.x * blockDim.x + threadIdx.x;
    if (tid >= B * F) return;
    int f = tid % F;
    int b = tid / F;
    const float vbf = vb[f], Af = A[f], thf = th[f], gf = gain[f];
    const float alpha = 0.001f;
    int rs = (int)fmaxf(ceilf(tref[f] / 0.05f), 1.0f);
    const float* xp = x + (size_t)b * T * F + f;
    float* va_out   = out + (size_t)b * (T + 1) * F + f;
    float* sp_out   = out + (size_t)B * (T + 1) * F + (size_t)b * (T + 1) * F + f;
    va_out[0] = vbf;
    float ema = 0.0f;
    int refc = 0;
    for (int t = 0; t < T; ++t) {
        float xt = xp[(size_t)t * F] * gf;
        float d1 = xt - ema;
        float emaN = ema + alpha * d1;
        ema = (t == 0) ? xt : emaN;
        float d2 = xt - ema;
        float va_cand = vbf - Af * d2;
        bool in_ref = refc > 0;
        bool cross = fabsf(va_cand - vbf) >= thf;
        bool fired = (!in_ref) && cross;
        float va_next = (in_ref || fired) ? vbf : va_cand;
        refc = in_ref ? (refc - 1) : refc;
        refc = fired ? rs : refc;
        va_out[(size_t)(t + 1) * F] = va_next;
        float spv = fired ? 1.0f : 0.0f;
        sp_out[(size_t)t * F] = spv;
        if (t == T - 1) sp_out[(size_t)T * F] = spv;
    }
}

extern "C" void kernel_launch(void* const* d_in, const int* in_sizes, int n_in,
                              void* d_out, int out_size, void* d_ws, size_t ws_size,
                              hipStream_t stream) {
    const float* x    = (const float*)d_in[0];
    const float* vb   = (const float*)d_in[1];
    const float* A    = (const float*)d_in[2];
    const float* th   = (const float*)d_in[3];
    const float* gain = (const float*)d_in[4];
    const float* tref = (const float*)d_in[5];
    float* out = (float*)d_out;

    int F = in_sizes[1];                                   // 512
    long long BF = (long long)out_size / 2 - in_sizes[0];  // B*F
    int B = (int)(BF / F);                                 // 16
    int T = (int)(in_sizes[0] / BF);                       // 4096
    int N = B * F;

    int nchunks = (T + L_CHUNK - 1) / L_CHUNK;
    size_t ws_need = (size_t)nchunks * N * (sizeof(float) + sizeof(int));

    if (ws_size < ws_need || (T % K1_UNROLL) != 0 || (T % L_CHUNK) != 0) {
        int block = 64;
        int grid = (N + block - 1) / block;
        fa_neuron_mono<<<grid, block, 0, stream>>>(x, vb, A, th, gain, tref, out, B, T, F);
        return;
    }

    float* emas = (float*)d_ws;
    int*   rins = (int*)(emas + (size_t)nchunks * N);

    {
        int block = 64;
        int grid = (N + block - 1) / block;
        fa_scan_kernel<<<grid, block, 0, stream>>>(x, vb, A, th, gain, tref,
                                                   emas, rins, B, T, F);
    }
    {
        int total = N * nchunks;
        int block = 256;
        int grid = (total + block - 1) / block;
        fa_emit_kernel<<<grid, block, 0, stream>>>(x, vb, A, th, gain, tref,
                                                   emas, rins, out, B, T, F, nchunks);
    }
}

// Round 3
// 225.952 us; speedup vs baseline: 1.4969x; 1.0637x over previous
//
#include <hip/hip_runtime.h>

// FANeuron two-pass:
//  K1 (scan): sequential per-chain recurrence, compute-only, stores exact
//             (ema, refc) state entering every L_CHUNK-step chunk.
//             Slimmed inner loop: peeled t==0, max-based refc update, and a
//             bit-exact fast path for (gain==1, A==1, vb==0).
//  K2 (emit): one thread per (chain, chunk) replays its chunk bit-exactly
//             from the seeded state and writes va_trace + spikes.

#define L_CHUNK 256
#define K1_UNROLL 32
#define K2_UNROLL 8

// General step. IS_FIRST statically selects the t==0 EMA init.
#define FA_STEP_GEN(XT, IS_FIRST)                                  \
    do {                                                           \
        float xt_ = (XT);                                          \
        if (IS_FIRST) {                                            \
            ema = xt_;                                             \
        } else {                                                   \
            float d1_ = xt_ - ema;                                 \
            float am_ = alpha * d1_;                               \
            ema = ema + am_;                                       \
        }                                                          \
        float d2_ = xt_ - ema;                                     \
        float av_ = Af * d2_;                                      \
        va_cand_ = vbf - av_;                                      \
        float dv_ = va_cand_ - vbf;                                \
        cross_ = fabsf(dv_) >= thf;                                \
        in_ref_ = refc > 0;                                        \
        fired_ = cross_ && !in_ref_;                               \
        int rd_ = refc - 1;                                        \
        rd_ = rd_ < 0 ? 0 : rd_;                                   \
        refc = fired_ ? rs : rd_;                                  \
    } while (0)

// Fast path: gain==1, A==1, vb==0 -> xt=x, va_cand=-d2, |va-vb|=|d2| (bit-exact).
#define FA_STEP_FAST(XT, IS_FIRST)                                 \
    do {                                                           \
        float xt_ = (XT);                                          \
        if (IS_FIRST) {                                            \
            ema = xt_;                                             \
        } else {                                                   \
            float d1_ = xt_ - ema;                                 \
            float am_ = alpha * d1_;                               \
            ema = ema + am_;                                       \
        }                                                          \
        float d2_ = xt_ - ema;                                     \
        va_cand_ = 0.0f - d2_;                                     \
        cross_ = fabsf(d2_) >= thf;                                \
        in_ref_ = refc > 0;                                        \
        fired_ = cross_ && !in_ref_;                               \
        int rd_ = refc - 1;                                        \
        rd_ = rd_ < 0 ? 0 : rd_;                                   \
        refc = fired_ ? rs : rd_;                                  \
    } while (0)

__global__ __launch_bounds__(64, 1)
void fa_scan_kernel(const float* __restrict__ x,
                    const float* __restrict__ vb,
                    const float* __restrict__ A,
                    const float* __restrict__ th,
                    const float* __restrict__ gain,
                    const float* __restrict__ tref,
                    float* __restrict__ emas,   // [nchunks][N]
                    int*   __restrict__ rins,   // [nchunks][N]
                    int B, int T, int F) {
#pragma clang fp contract(off)
    int N = B * F;
    int i = blockIdx.x * blockDim.x + threadIdx.x;
    if (i >= N) return;
    int f = i % F;
    int b = i / F;
    const float vbf = vb[f], Af = A[f], thf = th[f], gf = gain[f];
    const float alpha = 0.001f;                        // f32(0.05/50)
    int rs = (int)fmaxf(ceilf(tref[f] / 0.05f), 1.0f);
    const float* xp = x + (size_t)b * T * F + f;

    float ema = 0.0f;
    int refc = 0;
    float va_cand_;
    bool cross_, in_ref_, fired_;

    float cur[K1_UNROLL], nxt[K1_UNROLL];
#pragma unroll
    for (int u = 0; u < K1_UNROLL; ++u) cur[u] = xp[(size_t)u * F];

    bool fast = (gf == 1.0f) && (Af == 1.0f) && (vbf == 0.0f);

    if (fast) {
        for (int t0 = 0; t0 < T; t0 += K1_UNROLL) {
            if ((t0 & (L_CHUNK - 1)) == 0) {
                int k = t0 / L_CHUNK;
                emas[(size_t)k * N + i] = ema;
                rins[(size_t)k * N + i] = refc;
            }
            if (t0 + K1_UNROLL < T) {
#pragma unroll
                for (int u = 0; u < K1_UNROLL; ++u)
                    nxt[u] = xp[(size_t)(t0 + K1_UNROLL + u) * F];
            }
            bool first_blk = (t0 == 0);
#pragma unroll
            for (int u = 0; u < K1_UNROLL; ++u) {
                if (u == 0 && first_blk) FA_STEP_FAST(cur[u], true);
                else                     FA_STEP_FAST(cur[u], false);
            }
#pragma unroll
            for (int u = 0; u < K1_UNROLL; ++u) cur[u] = nxt[u];
        }
    } else {
        for (int t0 = 0; t0 < T; t0 += K1_UNROLL) {
            if ((t0 & (L_CHUNK - 1)) == 0) {
                int k = t0 / L_CHUNK;
                emas[(size_t)k * N + i] = ema;
                rins[(size_t)k * N + i] = refc;
            }
            if (t0 + K1_UNROLL < T) {
#pragma unroll
                for (int u = 0; u < K1_UNROLL; ++u)
                    nxt[u] = xp[(size_t)(t0 + K1_UNROLL + u) * F];
            }
            bool first_blk = (t0 == 0);
#pragma unroll
            for (int u = 0; u < K1_UNROLL; ++u) {
                float xt = cur[u] * gf;
                if (u == 0 && first_blk) FA_STEP_GEN(xt, true);
                else                     FA_STEP_GEN(xt, false);
            }
#pragma unroll
            for (int u = 0; u < K1_UNROLL; ++u) cur[u] = nxt[u];
        }
    }
}

__global__ __launch_bounds__(256)
void fa_emit_kernel(const float* __restrict__ x,
                    const float* __restrict__ vb,
                    const float* __restrict__ A,
                    const float* __restrict__ th,
                    const float* __restrict__ gain,
                    const float* __restrict__ tref,
                    const float* __restrict__ emas,
                    const int*   __restrict__ rins,
                    float* __restrict__ out,
                    int B, int T, int F, int nchunks) {
#pragma clang fp contract(off)
    int N = B * F;
    int tid = blockIdx.x * blockDim.x + threadIdx.x;
    if (tid >= N * nchunks) return;
    int i = tid % N;
    int k = tid / N;
    int f = i % F;
    int b = i / F;
    const float vbf = vb[f], Af = A[f], thf = th[f], gf = gain[f];
    const float alpha = 0.001f;
    int rs = (int)fmaxf(ceilf(tref[f] / 0.05f), 1.0f);

    const float* xp = x + (size_t)b * T * F + f;
    float* va_out   = out + (size_t)b * (T + 1) * F + f;
    float* sp_out   = out + (size_t)B * (T + 1) * F + (size_t)b * (T + 1) * F + f;

    float ema = emas[tid];
    int refc  = rins[tid];
    float va_cand_;
    bool cross_, in_ref_, fired_;
    if (k == 0) va_out[0] = vbf;   // va_trace[:,0,:] = vb

    int tbeg = k * L_CHUNK;
    int tend = tbeg + L_CHUNK;
    if (tend > T) tend = T;

    float cur[K2_UNROLL], nxt[K2_UNROLL];
#pragma unroll
    for (int u = 0; u < K2_UNROLL; ++u) cur[u] = xp[(size_t)(tbeg + u) * F];

    float last_sp = 0.0f;
    for (int t0 = tbeg; t0 < tend; t0 += K2_UNROLL) {
        if (t0 + K2_UNROLL < tend) {
#pragma unroll
            for (int u = 0; u < K2_UNROLL; ++u)
                nxt[u] = xp[(size_t)(t0 + K2_UNROLL + u) * F];
        }
        bool first_blk = (t0 == 0);
#pragma unroll
        for (int u = 0; u < K2_UNROLL; ++u) {
            int t = t0 + u;
            float xt = cur[u] * gf;
            if (u == 0 && first_blk) FA_STEP_GEN(xt, true);
            else                     FA_STEP_GEN(xt, false);
            float va_next = (in_ref_ || fired_) ? vbf : va_cand_;
            float spv = fired_ ? 1.0f : 0.0f;
            va_out[(size_t)(t + 1) * F] = va_next;
            sp_out[(size_t)t * F] = spv;
            last_sp = spv;
        }
#pragma unroll
        for (int u = 0; u < K2_UNROLL; ++u) cur[u] = nxt[u];
    }
    if (tend == T) sp_out[(size_t)T * F] = last_sp;   // spikes[:,T,:] = fired_{T-1}
}

// Fallback: monolithic (used only if ws too small / shape odd).
__global__ __launch_bounds__(64, 1)
void fa_neuron_mono(const float* __restrict__ x,
                    const float* __restrict__ vb,
                    const float* __restrict__ A,
                    const float* __restrict__ th,
                    const float* __restrict__ gain,
                    const float* __restrict__ tref,
                    float* __restrict__ out,
                    int B, int T, int F) {
#pragma clang fp contract(off)
    int tid = blockIdx.x * blockDim.x + threadIdx.x;
    if (tid >= B * F) return;
    int f = tid % F;
    int b = tid / F;
    const float vbf = vb[f], Af = A[f], thf = th[f], gf = gain[f];
    const float alpha = 0.001f;
    int rs = (int)fmaxf(ceilf(tref[f] / 0.05f), 1.0f);
    const float* xp = x + (size_t)b * T * F + f;
    float* va_out   = out + (size_t)b * (T + 1) * F + f;
    float* sp_out   = out + (size_t)B * (T + 1) * F + (size_t)b * (T + 1) * F + f;
    va_out[0] = vbf;
    float ema = 0.0f;
    int refc = 0;
    float va_cand_;
    bool cross_, in_ref_, fired_;
    for (int t = 0; t < T; ++t) {
        float xt = xp[(size_t)t * F] * gf;
        if (t == 0) FA_STEP_GEN(xt, true);
        else        FA_STEP_GEN(xt, false);
        float va_next = (in_ref_ || fired_) ? vbf : va_cand_;
        float spv = fired_ ? 1.0f : 0.0f;
        va_out[(size_t)(t + 1) * F] = va_next;
        sp_out[(size_t)t * F] = spv;
        if (t == T - 1) sp_out[(size_t)T * F] = spv;
    }
}

extern "C" void kernel_launch(void* const* d_in, const int* in_sizes, int n_in,
                              void* d_out, int out_size, void* d_ws, size_t ws_size,
                              hipStream_t stream) {
    const float* x    = (const float*)d_in[0];
    const float* vb   = (const float*)d_in[1];
    const float* A    = (const float*)d_in[2];
    const float* th   = (const float*)d_in[3];
    const float* gain = (const float*)d_in[4];
    const float* tref = (const float*)d_in[5];
    float* out = (float*)d_out;

    int F = in_sizes[1];                                   // 512
    long long BF = (long long)out_size / 2 - in_sizes[0];  // B*F
    int B = (int)(BF / F);                                 // 16
    int T = (int)(in_sizes[0] / BF);                       // 4096
    int N = B * F;

    int nchunks = (T + L_CHUNK - 1) / L_CHUNK;
    size_t ws_need = (size_t)nchunks * N * (sizeof(float) + sizeof(int));

    if (ws_size < ws_need || (T % K1_UNROLL) != 0 || (T % L_CHUNK) != 0) {
        int block = 64;
        int grid = (N + block - 1) / block;
        fa_neuron_mono<<<grid, block, 0, stream>>>(x, vb, A, th, gain, tref, out, B, T, F);
        return;
    }

    float* emas = (float*)d_ws;
    int*   rins = (int*)(emas + (size_t)nchunks * N);

    {
        int block = 64;
        int grid = (N + block - 1) / block;
        fa_scan_kernel<<<grid, block, 0, stream>>>(x, vb, A, th, gain, tref,
                                                   emas, rins, B, T, F);
    }
    {
        int total = N * nchunks;
        int block = 256;
        int grid = (total + block - 1) / block;
        fa_emit_kernel<<<grid, block, 0, stream>>>(x, vb, A, th, gain, tref,
                                                   emas, rins, out, B, T, F, nchunks);
    }
}